// Round 1
// baseline (85.050 us; speedup 1.0000x reference)
//
#include <hip/hip_runtime.h>

// GeometryAwareCostVolume — MI355X (gfx950)
//
// Algebraic restructuring vs reference:
//  * geo pyramid == feat pyramid (regularizer is identity): compute once, write twice.
//  * dx taps are integers -> floor(c/2^i + dx) = floor(c/2^i) + dx; single shared
//    lerp fraction per level; only 10 consecutive pooled bins needed per level.
//  * cost volume is linear in fmap2 -> pool fmap2 rows into a pyramid FIRST
//    (hierarchical pair means, exactly matching reference association), then one
//    dot8 per pooled bin. The 131 MB cost volume is never materialized.
//
// One block per (b,g,h): stage f2 row pyramid in LDS ([v][c] layout, 9.6 KB),
// thread w handles one output column (all 4 levels x 9 taps x 2 copies).

namespace {
constexpr int B_ = 2, C_ = 64, H_ = 80, W_ = 160;
constexpr int G_ = 8, GC_ = 8, L_ = 4, K_ = 9, R_ = 4;
constexpr int HW_ = H_ * W_;
constexpr int NCH_ = 2 * L_ * G_ * K_;  // 576 output channels
constexpr int TPB = 192;                 // 3 waves; 160 active in compute phase
constexpr float INV_SQRT_GC = 0.35355339059327373f;  // 1/sqrt(8)
}

__device__ __forceinline__ float dot8(const float* p, const float* f) {
  float4 a = *(const float4*)(p);
  float4 b = *(const float4*)(p + 4);
  return f[0] * a.x + f[1] * a.y + f[2] * a.z + f[3] * a.w +
         f[4] * b.x + f[5] * b.y + f[6] * b.z + f[7] * b.w;
}

__global__ __launch_bounds__(TPB) void gacv_kernel(
    const float* __restrict__ fmap1, const float* __restrict__ fmap2,
    const float* __restrict__ coords, float* __restrict__ out) {
  // f2-row pyramid, [v][c] layout (c contiguous -> ds_read_b128 taps)
  __shared__ __align__(16) float p0[W_ * GC_];        // 160 bins
  __shared__ __align__(16) float p1[(W_ / 2) * GC_];  // 80
  __shared__ __align__(16) float p2[(W_ / 4) * GC_];  // 40
  __shared__ __align__(16) float p3[(W_ / 8) * GC_];  // 20

  const int tid = threadIdx.x;
  const int bid = blockIdx.x;  // (b*G_ + g)*H_ + h
  const int h = bid % H_;
  const int bg = bid / H_;
  const int g = bg % G_;
  const int b = bg / G_;

  // ---- stage f2 row (transpose [c][v] -> [v][c]); lanes walk v => coalesced
  const float* f2base = fmap2 + (size_t)(b * C_ + g * GC_) * HW_ + h * W_;
  for (int idx = tid; idx < W_ * GC_; idx += TPB) {
    int v = idx % W_;
    int c = idx / W_;
    p0[v * GC_ + c] = f2base[c * HW_ + v];
  }
  __syncthreads();
  // ---- hierarchical pair-mean pyramid (matches reference association)
  for (int idx = tid; idx < (W_ / 2) * GC_; idx += TPB) {
    int c = idx & (GC_ - 1);
    p1[idx] = 0.5f * (p0[2 * idx - c] + p0[2 * idx - c + GC_]);
  }
  __syncthreads();
  for (int idx = tid; idx < (W_ / 4) * GC_; idx += TPB) {
    int c = idx & (GC_ - 1);
    p2[idx] = 0.5f * (p1[2 * idx - c] + p1[2 * idx - c + GC_]);
  }
  __syncthreads();
  for (int idx = tid; idx < (W_ / 8) * GC_; idx += TPB) {
    int c = idx & (GC_ - 1);
    p3[idx] = 0.5f * (p2[2 * idx - c] + p2[2 * idx - c + GC_]);
  }
  __syncthreads();

  if (tid >= W_) return;
  const int w = tid;

  // per-thread f1 fragment, pre-scaled by 1/sqrt(gc)
  float f1v[GC_];
  const float* f1base = fmap1 + (size_t)(b * C_ + g * GC_) * HW_ + h * W_ + w;
#pragma unroll
  for (int c = 0; c < GC_; ++c) f1v[c] = f1base[c * HW_] * INV_SQRT_GC;

  const float cx = coords[(b * H_ + h) * W_ + w];
  float* outb = out + (size_t)b * NCH_ * HW_ + h * W_ + w;
  const int gk = g * K_;

  const float* pyrs[4] = {p0, p1, p2, p3};
#pragma unroll
  for (int i = 0; i < L_; ++i) {
    const int Wl = W_ >> i;
    const float xl = cx * (1.0f / (1 << i));
    const float F = floorf(xl);
    const int fi = (int)F;
    const float w1 = xl - F;   // shared lerp fraction (dx taps are integers)
    const float w0 = 1.0f - w1;
    const float* pyr = pyrs[i];

    float T[2 * R_ + 2];  // pooled bins fi-4 .. fi+5, zero outside [0,Wl)
#pragma unroll
    for (int j = 0; j < 2 * R_ + 2; ++j) {
      int t = fi - R_ + j;
      int tc = min(max(t, 0), Wl - 1);
      float s = dot8(pyr + tc * GC_, f1v);
      T[j] = (t == tc) ? s : 0.0f;  // zero invalid taps (matches reference mask)
    }

    const int chBase = (2 * i) * (G_ * K_) + gk;
#pragma unroll
    for (int k = 0; k < K_; ++k) {
      float val = w0 * T[k] + w1 * T[k + 1];
      outb[(size_t)(chBase + k) * HW_] = val;              // "feat" copy
      outb[(size_t)(chBase + G_ * K_ + k) * HW_] = val;    // "geo" copy (identical)
    }
  }
}

extern "C" void kernel_launch(void* const* d_in, const int* in_sizes, int n_in,
                              void* d_out, int out_size, void* d_ws, size_t ws_size,
                              hipStream_t stream) {
  const float* fmap1 = (const float*)d_in[0];
  const float* fmap2 = (const float*)d_in[1];
  const float* coords = (const float*)d_in[2];
  float* out = (float*)d_out;
  gacv_kernel<<<dim3(B_ * G_ * H_), dim3(TPB), 0, stream>>>(fmap1, fmap2, coords, out);
}